// Round 2
// baseline (275.519 us; speedup 1.0000x reference)
//
#include <hip/hip_runtime.h>
#include <hip/hip_fp16.h>

#define NW 18
#define NSTATE (1u << NW)                      // 262144 per batch
#define NBATCH 32
#define TOTAL (NBATCH * (size_t)NSTATE)        // 8388608 elements

struct Masks { unsigned m[18]; };

// complex 2x2 butterfly, explicit FMA: 4 outputs x (1 mul + 3 fma) = 16 VALU ops
__device__ __forceinline__ void bfly(float2& a, float2& b, const float4 g0, const float4 g1) {
    float ax = a.x, ay = a.y, bx = b.x, by = b.y;
    float nax = fmaf(g0.x, ax, fmaf(-g0.y, ay, fmaf(g0.z, bx, -(g0.w*by))));
    float nay = fmaf(g0.x, ay, fmaf( g0.y, ax, fmaf(g0.z, by,  (g0.w*bx))));
    float nbx = fmaf(g1.x, ax, fmaf(-g1.y, ay, fmaf(g1.z, bx, -(g1.w*by))));
    float nby = fmaf(g1.x, ay, fmaf( g1.y, ax, fmaf(g1.z, by,  (g1.w*bx))));
    a.x = nax; a.y = nay; b.x = nbx; b.y = nby;
}

__device__ __forceinline__ int swz(int n) { return n ^ ((n >> 5) & 31); }

// compile-time ctz for the gray-code scatter
__device__ __forceinline__ constexpr int ctzc(int x) {
    int c = 0; while (!(x & 1)) { x >>= 1; c++; } return c;
}

// ---- gate matrices from params + zero the norm accumulators -------------------
__global__ void prep(const float* __restrict__ params, float4* __restrict__ Utab,
                     float* __restrict__ norms) {
    int i = threadIdx.x;
    if (i < 36) {
        float phi = params[i*3+0], th = params[i*3+1], om = params[i*3+2];
        float ch = cosf(th*0.5f), sh = sinf(th*0.5f);
        float a0 = -0.5f*(phi+om);
        float a1 =  0.5f*(phi-om);
        float c0 = cosf(a0), s0 = sinf(a0);
        float c1 = cosf(a1), s1 = sinf(a1);
        Utab[i*2+0] = make_float4(c0*ch,  s0*ch, -c1*sh, -s1*sh);
        Utab[i*2+1] = make_float4(c1*sh, -s1*sh,  c0*ch, -s0*ch);
    }
    if (i >= 64 && i < 96) norms[i-64] = 0.f;
}

// ---- per-batch sum of squares -------------------------------------------------
__global__ __launch_bounds__(256) void normk(const float* __restrict__ x,
                                             float* __restrict__ norms) {
    int t = threadIdx.x;
    size_t base = (size_t)blockIdx.x * 4096;
    int batch = (int)(base >> NW);
    const float4* p = (const float4*)(x + base);
    float s = 0.f;
#pragma unroll
    for (int j = 0; j < 4; j++) {
        float4 q = p[t + j*256];
        s += q.x*q.x + q.y*q.y + q.z*q.z + q.w*q.w;
    }
#pragma unroll
    for (int m = 32; m >= 1; m >>= 1) s += __shfl_xor(s, m, 64);
    __shared__ float ws[4];
    if ((t & 63) == 0) ws[t >> 6] = s;
    __syncthreads();
    if (t == 0) atomicAdd(&norms[batch], ws[0]+ws[1]+ws[2]+ws[3]);
}

// ---- pass A: butterflies on bits 0..12 within contiguous 8192 blocks ----------
template<int SRC_F32>
__global__ __launch_bounds__(256, 4) void passA(const void* __restrict__ src,
                                                __half2* __restrict__ dst,
                                                const float4* __restrict__ Utab,
                                                const float* __restrict__ norms,
                                                int layer) {
    __shared__ __half2 sm[8192];   // 32 KB
    const int t = threadIdx.x;
    const size_t base = (size_t)blockIdx.x * 8192;
    float2 v[32];

    if (SRC_F32) {
        const float* xs = (const float*)src + base + (size_t)t * 32;
        float sc = 1.0f / sqrtf(norms[base >> NW]);
#pragma unroll
        for (int j = 0; j < 8; j++) {
            float4 q = ((const float4*)xs)[j];
            v[j*4+0] = make_float2(q.x*sc, 0.f);
            v[j*4+1] = make_float2(q.y*sc, 0.f);
            v[j*4+2] = make_float2(q.z*sc, 0.f);
            v[j*4+3] = make_float2(q.w*sc, 0.f);
        }
    } else {
        const __half2* xs = (const __half2*)src + base + (size_t)t * 32;
#pragma unroll
        for (int j = 0; j < 8; j++) {
            float4 q = ((const float4*)xs)[j];
            const __half2* h = (const __half2*)&q;
            v[j*4+0] = __half22float2(h[0]);
            v[j*4+1] = __half22float2(h[1]);
            v[j*4+2] = __half22float2(h[2]);
            v[j*4+3] = __half22float2(h[3]);
        }
    }

    const float4* Ut = Utab + (size_t)layer * 36;   // 18 gates * 2 float4

    // stages on bits 0..4 (wire 17-b); element k has bits 0..4 of local index
#pragma unroll
    for (int b = 0; b < 5; b++) {
        float4 g0 = Ut[(17-b)*2+0], g1 = Ut[(17-b)*2+1];
#pragma unroll
        for (int k = 0; k < 32; k++)
            if (!(k & (1 << b))) bfly(v[k], v[k | (1 << b)], g0, g1);
    }

    // exchange 1: tile1 n = t*32+k  ->  tile2 n = (t&31) | k<<5 | (t>>5)<<10
#pragma unroll
    for (int k = 0; k < 32; k++) {
        int n = t*32 + k;
        sm[swz(n)] = __floats2half2_rn(v[k].x, v[k].y);
    }
    __syncthreads();
#pragma unroll
    for (int k = 0; k < 32; k++) {
        int n = (t & 31) | (k << 5) | ((t >> 5) << 10);
        v[k] = __half22float2(sm[swz(n)]);
    }

    // stages on bits 5..9  (k bit b-5)
#pragma unroll
    for (int b = 5; b < 10; b++) {
        float4 g0 = Ut[(17-b)*2+0], g1 = Ut[(17-b)*2+1];
        int pb = 1 << (b - 5);
#pragma unroll
        for (int k = 0; k < 32; k++)
            if (!(k & pb)) bfly(v[k], v[k | pb], g0, g1);
    }

    // exchange 2: write back tile2 slots (same slots we read), then read tile3
#pragma unroll
    for (int k = 0; k < 32; k++) {
        int n = (t & 31) | (k << 5) | ((t >> 5) << 10);
        sm[swz(n)] = __floats2half2_rn(v[k].x, v[k].y);
    }
    __syncthreads();
#pragma unroll
    for (int k = 0; k < 32; k++) {
        int n = (t & 31) | ((t >> 5) << 5) | ((k & 3) << 8) | ((k >> 2) << 10);
        v[k] = __half22float2(sm[swz(n)]);
    }

    // stages on bits 10..12 (k bit b-8)
#pragma unroll
    for (int b = 10; b < 13; b++) {
        float4 g0 = Ut[(17-b)*2+0], g1 = Ut[(17-b)*2+1];
        int pb = 1 << (b - 8);
#pragma unroll
        for (int k = 0; k < 32; k++)
            if (!(k & pb)) bfly(v[k], v[k | pb], g0, g1);
    }

    // store (tile3 layout: lane-contiguous, coalesced)
#pragma unroll
    for (int k = 0; k < 32; k++) {
        int n = (t & 31) | ((t >> 5) << 5) | ((k & 3) << 8) | ((k >> 2) << 10);
        dst[base + n] = __floats2half2_rn(v[k].x, v[k].y);
    }
}

// ---- pass B: butterflies on bits 13..17, then CNOT-chain scatter --------------
// LAST=1: write |amp| as f32 to out; else half2 state.
template<int LAST>
__global__ __launch_bounds__(256, 4) void passB(const __half2* __restrict__ src,
                                                void* __restrict__ dst,
                                                const float4* __restrict__ Utab,
                                                int layer, Masks mk) {
    const unsigned tid = blockIdx.x * 256 + threadIdx.x;   // 0 .. 2^18-1
    const unsigned batch = tid >> 13;
    const unsigned lo = tid & 8191u;
    const size_t bb = (size_t)batch << NW;
    float2 v[32];
#pragma unroll
    for (int s = 0; s < 32; s++)
        v[s] = __half22float2(src[bb + ((unsigned)s << 13) + lo]);

    const float4* Ut = Utab + (size_t)layer * 36;
#pragma unroll
    for (int b = 13; b < 18; b++) {
        float4 g0 = Ut[(17-b)*2+0], g1 = Ut[(17-b)*2+1];
        int pb = 1 << (b - 13);
#pragma unroll
        for (int s = 0; s < 32; s++)
            if (!(s & pb)) bfly(v[s], v[s | pb], g0, g1);
    }

    // scatter through the GF(2)-linear CNOT-chain map
    unsigned f = 0;
#pragma unroll
    for (int k = 0; k < 13; k++) f ^= ((lo >> k) & 1u) ? mk.m[k] : 0u;

    // gray-code order: one mask XOR per step instead of popcount(s)
    unsigned fs = f;
#pragma unroll
    for (int i = 0; i < 32; i++) {
        if (i) fs ^= mk.m[13 + ctzc(i)];
        const int s = i ^ (i >> 1);
        if (LAST) {
            ((float*)dst)[bb + fs] = sqrtf(fmaf(v[s].x, v[s].x, v[s].y*v[s].y));
        } else {
            ((__half2*)dst)[bb + fs] = __floats2half2_rn(v[s].x, v[s].y);
        }
    }
}

// ---- host: CNOT chain as an 18x18 GF(2) matrix -> column masks ----------------
static void chain_masks(int l, Masks* mk) {
    unsigned rows[18];
    for (int j = 0; j < 18; j++) rows[j] = 1u << j;      // new bit j as fn of old bits
    for (int i = 0; i < 18; i++) {
        int cw = (i + l) % 18, tw = (i + l + 1) % 18;    // wires
        rows[17 - tw] ^= rows[17 - cw];                  // bit_t ^= bit_c
    }
    for (int k = 0; k < 18; k++) {                       // transpose into column masks
        unsigned cm = 0;
        for (int j = 0; j < 18; j++) cm |= ((rows[j] >> k) & 1u) << j;
        mk->m[k] = cm;
    }
}

extern "C" void kernel_launch(void* const* d_in, const int* in_sizes, int n_in,
                              void* d_out, int out_size, void* d_ws, size_t ws_size,
                              hipStream_t stream) {
    const float* x      = (const float*)d_in[0];
    const float* params = (const float*)d_in[1];

    char* ws = (char*)d_ws;
    __half2* bufA = (__half2*)ws;                        // 32 MB
    __half2* bufB = (__half2*)(ws + TOTAL * 4);          // 32 MB
    float4*  Utab = (float4*)(ws + TOTAL * 8);           // 72 * 16 B
    float*   norms = (float*)(ws + TOTAL * 8 + 4096);    // 32 f32

    Masks mk1, mk2;
    chain_masks(0, &mk1);
    chain_masks(1, &mk2);

    prep<<<1, 96, 0, stream>>>(params, Utab, norms);
    normk<<<2048, 256, 0, stream>>>(x, norms);
    passA<1><<<1024, 256, 0, stream>>>((const void*)x, bufA, Utab, norms, 0);
    passB<0><<<1024, 256, 0, stream>>>(bufA, (void*)bufB, Utab, 0, mk1);
    passA<0><<<1024, 256, 0, stream>>>((const void*)bufB, bufB, Utab, norms, 1);
    passB<1><<<1024, 256, 0, stream>>>(bufB, d_out, Utab, 1, mk2);
}

// Round 3
// 183.514 us; speedup vs baseline: 1.5014x; 1.5014x over previous
//
#include <hip/hip_runtime.h>
#include <hip/hip_fp16.h>

#define NW 18
#define NSTATE (1u << NW)                      // 262144 per batch
#define NBATCH 32
#define TOTAL (NBATCH * (size_t)NSTATE)        // 8388608 elements

struct Masks { unsigned m[18]; };

// complex 2x2 butterfly, explicit FMA: 4 outputs x (1 mul + 3 fma) = 16 VALU ops
__device__ __forceinline__ void bfly(float2& a, float2& b, const float4 g0, const float4 g1) {
    float ax = a.x, ay = a.y, bx = b.x, by = b.y;
    float nax = fmaf(g0.x, ax, fmaf(-g0.y, ay, fmaf(g0.z, bx, -(g0.w*by))));
    float nay = fmaf(g0.x, ay, fmaf( g0.y, ax, fmaf(g0.z, by,  (g0.w*bx))));
    float nbx = fmaf(g1.x, ax, fmaf(-g1.y, ay, fmaf(g1.z, bx, -(g1.w*by))));
    float nby = fmaf(g1.x, ay, fmaf( g1.y, ax, fmaf(g1.z, by,  (g1.w*bx))));
    a.x = nax; a.y = nay; b.x = nbx; b.y = nby;
}

__device__ __forceinline__ int swz(int n) { return n ^ ((n >> 5) & 31); }

__device__ __forceinline__ constexpr int ctzc(int x) {
    int c = 0; while (!(x & 1)) { x >>= 1; c++; } return c;
}

// ---- gate matrices from params + zero the norm accumulators -------------------
__global__ void prep(const float* __restrict__ params, float4* __restrict__ Utab,
                     float* __restrict__ norms) {
    int i = threadIdx.x;
    if (i < 36) {
        float phi = params[i*3+0], th = params[i*3+1], om = params[i*3+2];
        float ch = cosf(th*0.5f), sh = sinf(th*0.5f);
        float a0 = -0.5f*(phi+om);
        float a1 =  0.5f*(phi-om);
        float c0 = cosf(a0), s0 = sinf(a0);
        float c1 = cosf(a1), s1 = sinf(a1);
        Utab[i*2+0] = make_float4(c0*ch,  s0*ch, -c1*sh, -s1*sh);
        Utab[i*2+1] = make_float4(c1*sh, -s1*sh,  c0*ch, -s0*ch);
    }
    if (i >= 64 && i < 96) norms[i-64] = 0.f;
}

// ---- per-batch sum of squares -------------------------------------------------
__global__ __launch_bounds__(256) void normk(const float* __restrict__ x,
                                             float* __restrict__ norms) {
    int t = threadIdx.x;
    size_t base = (size_t)blockIdx.x * 4096;
    int batch = (int)(base >> NW);
    const float4* p = (const float4*)(x + base);
    float s = 0.f;
#pragma unroll
    for (int j = 0; j < 4; j++) {
        float4 q = p[t + j*256];
        s += q.x*q.x + q.y*q.y + q.z*q.z + q.w*q.w;
    }
#pragma unroll
    for (int m = 32; m >= 1; m >>= 1) s += __shfl_xor(s, m, 64);
    __shared__ float ws[4];
    if ((t & 63) == 0) ws[t >> 6] = s;
    __syncthreads();
    if (t == 0) atomicAdd(&norms[batch], ws[0]+ws[1]+ws[2]+ws[3]);
}

// ---- pass A: butterflies on bits 0..11 within contiguous 8192 blocks ----------
// 512 threads x 16 elems; 3 register phases of 4 bits, 2 LDS exchanges.
template<int SRC_F32>
__global__ __launch_bounds__(512, 4) void passA(const void* __restrict__ src,
                                                __half2* __restrict__ dst,
                                                const float4* __restrict__ Utab,
                                                const float* __restrict__ norms,
                                                int layer) {
    __shared__ __half2 sm[8192];   // 32 KB
    const int t = threadIdx.x;     // 0..511
    const size_t base = (size_t)blockIdx.x * 8192;
    float2 v[16];

    if (SRC_F32) {
        const float* xs = (const float*)src + base + (size_t)t * 16;
        float sc = 1.0f / sqrtf(norms[base >> NW]);
#pragma unroll
        for (int j = 0; j < 4; j++) {
            float4 q = ((const float4*)xs)[j];
            v[j*4+0] = make_float2(q.x*sc, 0.f);
            v[j*4+1] = make_float2(q.y*sc, 0.f);
            v[j*4+2] = make_float2(q.z*sc, 0.f);
            v[j*4+3] = make_float2(q.w*sc, 0.f);
        }
    } else {
        const __half2* xs = (const __half2*)src + base + (size_t)t * 16;
#pragma unroll
        for (int j = 0; j < 4; j++) {
            float4 q = ((const float4*)xs)[j];
            const __half2* h = (const __half2*)&q;
            v[j*4+0] = __half22float2(h[0]);
            v[j*4+1] = __half22float2(h[1]);
            v[j*4+2] = __half22float2(h[2]);
            v[j*4+3] = __half22float2(h[3]);
        }
    }

    const float4* Ut = Utab + (size_t)layer * 36;   // 18 gates * 2 float4

    // phase 1: bits 0..3 (element k = n&15)
#pragma unroll
    for (int b = 0; b < 4; b++) {
        float4 g0 = Ut[(17-b)*2+0], g1 = Ut[(17-b)*2+1];
#pragma unroll
        for (int k = 0; k < 16; k++)
            if (!(k & (1 << b))) bfly(v[k], v[k | (1 << b)], g0, g1);
    }

    // exchange 1: L1 n = (t<<4)|k  ->  L2 n = (t&15) | k<<4 | (t>>4)<<8
#pragma unroll
    for (int k = 0; k < 16; k++) {
        int n = (t << 4) | k;
        sm[swz(n)] = __floats2half2_rn(v[k].x, v[k].y);
    }
    __syncthreads();
#pragma unroll
    for (int k = 0; k < 16; k++) {
        int n = (t & 15) | (k << 4) | ((t >> 4) << 8);
        v[k] = __half22float2(sm[swz(n)]);
    }

    // phase 2: bits 4..7 (element k = (n>>4)&15)
#pragma unroll
    for (int b = 4; b < 8; b++) {
        float4 g0 = Ut[(17-b)*2+0], g1 = Ut[(17-b)*2+1];
        int pb = 1 << (b - 4);
#pragma unroll
        for (int k = 0; k < 16; k++)
            if (!(k & pb)) bfly(v[k], v[k | pb], g0, g1);
    }

    // exchange 2: write back own L2 slots (no sync needed), then read L3
#pragma unroll
    for (int k = 0; k < 16; k++) {
        int n = (t & 15) | (k << 4) | ((t >> 4) << 8);
        sm[swz(n)] = __floats2half2_rn(v[k].x, v[k].y);
    }
    __syncthreads();
#pragma unroll
    for (int k = 0; k < 16; k++) {
        int n = (t & 255) | (k << 8) | ((t >> 8) << 12);
        v[k] = __half22float2(sm[swz(n)]);
    }

    // phase 3: bits 8..11 (element k = (n>>8)&15)
#pragma unroll
    for (int b = 8; b < 12; b++) {
        float4 g0 = Ut[(17-b)*2+0], g1 = Ut[(17-b)*2+1];
        int pb = 1 << (b - 8);
#pragma unroll
        for (int k = 0; k < 16; k++)
            if (!(k & pb)) bfly(v[k], v[k | pb], g0, g1);
    }

    // store (L3 layout: lane-contiguous, coalesced)
#pragma unroll
    for (int k = 0; k < 16; k++) {
        int n = (t & 255) | (k << 8) | ((t >> 8) << 12);
        dst[base + n] = __floats2half2_rn(v[k].x, v[k].y);
    }
}

// ---- pass B: butterflies on bits 12..17, then CNOT-chain scatter --------------
// 512 threads x 16 elems. Block = 128 contiguous lows x all 64 highs.
// Phase 1: bits 12..15 in registers; LDS exchange; phase 2: bits 16..17; scatter.
// LAST=1: write |amp| as f32 to out; else half2 state.
template<int LAST>
__global__ __launch_bounds__(512, 4) void passB(const __half2* __restrict__ src,
                                                void* __restrict__ dst,
                                                const float4* __restrict__ Utab,
                                                int layer, Masks mk) {
    __shared__ __half2 sm[8192];   // 32 KB
    const int t = threadIdx.x;                 // 0..511
    const unsigned blk = blockIdx.x;           // 1024 blocks
    const unsigned batch = blk >> 5;
    const unsigned chunk = blk & 31;
    const unsigned low = chunk * 128 + (t & 127);   // 12-bit low index
    const unsigned j = t >> 7;                 // 0..3
    const size_t bb = (size_t)batch << NW;

    float2 v[16];
    // phase-1 ownership: h = (j<<4) | k  (k = h bits 0..3 = state bits 12..15)
#pragma unroll
    for (int k = 0; k < 16; k++) {
        unsigned h = (j << 4) | k;
        v[k] = __half22float2(src[bb + ((size_t)h << 12) + low]);
    }

    const float4* Ut = Utab + (size_t)layer * 36;
#pragma unroll
    for (int b = 12; b < 16; b++) {
        float4 g0 = Ut[(17-b)*2+0], g1 = Ut[(17-b)*2+1];
        int pb = 1 << (b - 12);
#pragma unroll
        for (int k = 0; k < 16; k++)
            if (!(k & pb)) bfly(v[k], v[k | pb], g0, g1);
    }

    // exchange: slot n = (h<<7) | (t&127); bank = t&31 -> 2-way, free
#pragma unroll
    for (int k = 0; k < 16; k++) {
        unsigned h = (j << 4) | k;
        sm[(h << 7) | (t & 127)] = __floats2half2_rn(v[k].x, v[k].y);
    }
    __syncthreads();
    // phase-2 ownership: h = (q<<4) | (j<<2) | r, element idx = (q<<2)|r
#pragma unroll
    for (int q = 0; q < 4; q++)
#pragma unroll
        for (int r = 0; r < 4; r++) {
            unsigned h = (q << 4) | (j << 2) | r;
            v[(q << 2) | r] = __half22float2(sm[(h << 7) | (t & 127)]);
        }

    // bit 16 (wire 1): pairs idx, idx^4 ; bit 17 (wire 0): pairs idx, idx^8
    {
        float4 g0 = Ut[1*2+0], g1 = Ut[1*2+1];
#pragma unroll
        for (int k = 0; k < 16; k++)
            if (!(k & 4)) bfly(v[k], v[k | 4], g0, g1);
        g0 = Ut[0]; g1 = Ut[1];
#pragma unroll
        for (int k = 0; k < 16; k++)
            if (!(k & 8)) bfly(v[k], v[k | 8], g0, g1);
    }

    // scatter through GF(2)-linear CNOT map. Per-thread fixed part:
    unsigned f = 0;
#pragma unroll
    for (int kk = 0; kk < 12; kk++) f ^= ((low >> kk) & 1u) ? mk.m[kk] : 0u;
    if (j & 1) f ^= mk.m[14];
    if (j & 2) f ^= mk.m[15];

    // element idx bits: r0->m12, r1->m13, q0->m16, q1->m17 ; gray-code walk
    const unsigned gm0 = mk.m[12], gm1 = mk.m[13], gm2 = mk.m[16], gm3 = mk.m[17];
    unsigned fs = f;
#pragma unroll
    for (int i = 0; i < 16; i++) {
        if (i) {
            const int c = ctzc(i);
            fs ^= (c == 0) ? gm0 : (c == 1) ? gm1 : (c == 2) ? gm2 : gm3;
        }
        const int s = i ^ (i >> 1);
        if (LAST) {
            ((float*)dst)[bb + fs] = sqrtf(fmaf(v[s].x, v[s].x, v[s].y*v[s].y));
        } else {
            ((__half2*)dst)[bb + fs] = __floats2half2_rn(v[s].x, v[s].y);
        }
    }
}

// ---- host: CNOT chain as an 18x18 GF(2) matrix -> column masks ----------------
static void chain_masks(int l, Masks* mk) {
    unsigned rows[18];
    for (int j = 0; j < 18; j++) rows[j] = 1u << j;      // new bit j as fn of old bits
    for (int i = 0; i < 18; i++) {
        int cw = (i + l) % 18, tw = (i + l + 1) % 18;    // wires
        rows[17 - tw] ^= rows[17 - cw];                  // bit_t ^= bit_c
    }
    for (int k = 0; k < 18; k++) {                       // transpose into column masks
        unsigned cm = 0;
        for (int j = 0; j < 18; j++) cm |= ((rows[j] >> k) & 1u) << j;
        mk->m[k] = cm;
    }
}

extern "C" void kernel_launch(void* const* d_in, const int* in_sizes, int n_in,
                              void* d_out, int out_size, void* d_ws, size_t ws_size,
                              hipStream_t stream) {
    const float* x      = (const float*)d_in[0];
    const float* params = (const float*)d_in[1];

    char* ws = (char*)d_ws;
    __half2* bufA = (__half2*)ws;                        // 32 MB
    __half2* bufB = (__half2*)(ws + TOTAL * 4);          // 32 MB
    float4*  Utab = (float4*)(ws + TOTAL * 8);           // 72 * 16 B
    float*   norms = (float*)(ws + TOTAL * 8 + 4096);    // 32 f32

    Masks mk1, mk2;
    chain_masks(0, &mk1);
    chain_masks(1, &mk2);

    prep<<<1, 96, 0, stream>>>(params, Utab, norms);
    normk<<<2048, 256, 0, stream>>>(x, norms);
    passA<1><<<1024, 512, 0, stream>>>((const void*)x, bufA, Utab, norms, 0);
    passB<0><<<1024, 512, 0, stream>>>(bufA, (void*)bufB, Utab, 0, mk1);
    passA<0><<<1024, 512, 0, stream>>>((const void*)bufB, bufB, Utab, norms, 1);
    passB<1><<<1024, 512, 0, stream>>>(bufB, d_out, Utab, 1, mk2);
}

// Round 4
// 158.520 us; speedup vs baseline: 1.7381x; 1.1577x over previous
//
#include <hip/hip_runtime.h>
#include <hip/hip_fp16.h>

#define NW 18
#define NSTATE (1u << NW)                      // 262144 per batch
#define NBATCH 32
#define TOTAL (NBATCH * (size_t)NSTATE)        // 8388608 elements

typedef float v2f __attribute__((ext_vector_type(2)));
typedef _Float16 h2v __attribute__((ext_vector_type(2)));

struct Masks { unsigned m[18]; };

// ---- packed complex arithmetic via VOP3P op_sel/neg folding -------------------
// g = (re, im) complex gate coeff; a/b = (re, im) amplitudes.
__device__ __forceinline__ v2f pk_mulsw(v2f g, v2f b) {   // (-g.im*b.im, g.im*b.re)
    v2f d;
    asm("v_pk_mul_f32 %0, %1, %2 op_sel:[1,1] op_sel_hi:[1,0] neg_lo:[1,0]"
        : "=v"(d) : "v"(g), "v"(b));
    return d;
}
__device__ __forceinline__ v2f pk_fmare(v2f g, v2f a, v2f c) { // (g.re*a.re+c.x, g.re*a.im+c.y)
    v2f d;
    asm("v_pk_fma_f32 %0, %1, %2, %3 op_sel:[0,0,0] op_sel_hi:[0,1,1]"
        : "=v"(d) : "v"(g), "v"(a), "v"(c));
    return d;
}
__device__ __forceinline__ v2f pk_fmasw(v2f g, v2f a, v2f c) { // (-g.im*a.im+c.x, g.im*a.re+c.y)
    v2f d;
    asm("v_pk_fma_f32 %0, %1, %2, %3 op_sel:[1,1,0] op_sel_hi:[1,0,1] neg_lo:[1,0,0]"
        : "=v"(d) : "v"(g), "v"(a), "v"(c));
    return d;
}
__device__ __forceinline__ v2f cmul(v2f g, v2f x) { return pk_fmare(g, x, pk_mulsw(g, x)); }
__device__ __forceinline__ v2f cmad(v2f g, v2f x, v2f c) { return pk_fmare(g, x, pk_fmasw(g, x, c)); }

// butterfly: (a,b) <- (g00*a + g01*b, g10*a + g11*b) : 8 VOP3P insts
__device__ __forceinline__ void bfly(v2f& a, v2f& b, v2f g00, v2f g01, v2f g10, v2f g11) {
    v2f na = cmad(g00, a, cmul(g01, b));
    v2f nb = cmad(g10, a, cmul(g11, b));
    a = na; b = nb;
}

// fp16x2 pack/unpack (RTZ pack = 1 inst)
__device__ __forceinline__ unsigned pack(v2f v) {
    return __builtin_bit_cast(unsigned, __builtin_amdgcn_cvt_pkrtz(v.x, v.y));
}
__device__ __forceinline__ v2f unpack(unsigned u) {
    h2v h = __builtin_bit_cast(h2v, u);
    return (v2f){(float)h.x, (float)h.y};
}

__device__ __forceinline__ int swz(int n) { return n ^ ((n >> 5) & 31); }

__device__ __forceinline__ constexpr int ctzc(int x) {
    int c = 0; while (!(x & 1)) { x >>= 1; c++; } return c;
}

#define GATES(gb)                                                      \
    const float4 G0_ = Ut[(17-(gb))*2+0], G1_ = Ut[(17-(gb))*2+1];     \
    const v2f g00 = {G0_.x, G0_.y}, g01 = {G0_.z, G0_.w};              \
    const v2f g10 = {G1_.x, G1_.y}, g11 = {G1_.z, G1_.w};

// ---- gate matrices from params ------------------------------------------------
__global__ void prep(const float* __restrict__ params, float4* __restrict__ Utab) {
    int i = threadIdx.x;
    if (i < 36) {
        float phi = params[i*3+0], th = params[i*3+1], om = params[i*3+2];
        float ch = cosf(th*0.5f), sh = sinf(th*0.5f);
        float a0 = -0.5f*(phi+om);
        float a1 =  0.5f*(phi-om);
        float c0 = cosf(a0), s0 = sinf(a0);
        float c1 = cosf(a1), s1 = sinf(a1);
        Utab[i*2+0] = make_float4(c0*ch,  s0*ch, -c1*sh, -s1*sh);
        Utab[i*2+1] = make_float4(c1*sh, -s1*sh,  c0*ch, -s0*ch);
    }
}

// ---- per-chunk sum of squares (no atomics; 64 partials per batch) -------------
__global__ __launch_bounds__(256) void normk(const float* __restrict__ x,
                                             float* __restrict__ partials) {
    int t = threadIdx.x;
    size_t base = (size_t)blockIdx.x * 4096;
    const float4* p = (const float4*)(x + base);
    float s = 0.f;
#pragma unroll
    for (int j = 0; j < 4; j++) {
        float4 q = p[t + j*256];
        s += q.x*q.x + q.y*q.y + q.z*q.z + q.w*q.w;
    }
#pragma unroll
    for (int m = 32; m >= 1; m >>= 1) s += __shfl_xor(s, m, 64);
    __shared__ float ws[4];
    if ((t & 63) == 0) ws[t >> 6] = s;
    __syncthreads();
    if (t == 0) partials[blockIdx.x] = ws[0]+ws[1]+ws[2]+ws[3];
}

// ---- pass A: butterflies on bits 0..11 within contiguous 4096 blocks ----------
// 256 threads x 16 elems; 3 register phases of 4 bits, 2 LDS exchanges.
// State is UNSCALED (norm folded into final pass).
template<int SRC_F32>
__global__ __launch_bounds__(256, 4) void passA(const void* __restrict__ src,
                                                unsigned* __restrict__ dst,
                                                const float4* __restrict__ Utab,
                                                int layer) {
    __shared__ unsigned sm[4096];   // 16 KB
    const int t = threadIdx.x;      // 0..255
    const size_t base = (size_t)blockIdx.x * 4096;
    v2f v[16];

    if (SRC_F32) {
        const float4* xs = (const float4*)((const float*)src + base + (size_t)t * 16);
#pragma unroll
        for (int j = 0; j < 4; j++) {
            float4 q = xs[j];
            v[j*4+0] = (v2f){q.x, 0.f};
            v[j*4+1] = (v2f){q.y, 0.f};
            v[j*4+2] = (v2f){q.z, 0.f};
            v[j*4+3] = (v2f){q.w, 0.f};
        }
    } else {
        const uint4* xs = (const uint4*)((const unsigned*)src + base + (size_t)t * 16);
#pragma unroll
        for (int j = 0; j < 4; j++) {
            uint4 q = xs[j];
            v[j*4+0] = unpack(q.x);
            v[j*4+1] = unpack(q.y);
            v[j*4+2] = unpack(q.z);
            v[j*4+3] = unpack(q.w);
        }
    }

    const float4* Ut = Utab + (size_t)layer * 36;   // 18 gates * 2 float4

    // phase 1: bits 0..3 (element k = n&15)
#pragma unroll
    for (int b = 0; b < 4; b++) {
        GATES(b);
#pragma unroll
        for (int k = 0; k < 16; k++)
            if (!(k & (1 << b))) bfly(v[k], v[k | (1 << b)], g00, g01, g10, g11);
    }

    // exchange 1: L1 n = (t<<4)|k  ->  L2 n = (t&15) | k<<4 | (t>>4)<<8
#pragma unroll
    for (int k = 0; k < 16; k++)
        sm[swz((t << 4) | k)] = pack(v[k]);
    __syncthreads();
#pragma unroll
    for (int k = 0; k < 16; k++)
        v[k] = unpack(sm[swz((t & 15) | (k << 4) | ((t >> 4) << 8))]);

    // phase 2: bits 4..7 (element k = (n>>4)&15)
#pragma unroll
    for (int b = 4; b < 8; b++) {
        GATES(b);
        const int pb = 1 << (b - 4);
#pragma unroll
        for (int k = 0; k < 16; k++)
            if (!(k & pb)) bfly(v[k], v[k | pb], g00, g01, g10, g11);
    }

    // exchange 2: write back own L2 slots (disjoint, no pre-sync), read L3
#pragma unroll
    for (int k = 0; k < 16; k++)
        sm[swz((t & 15) | (k << 4) | ((t >> 4) << 8))] = pack(v[k]);
    __syncthreads();
#pragma unroll
    for (int k = 0; k < 16; k++)
        v[k] = unpack(sm[swz(t | (k << 8))]);

    // phase 3: bits 8..11 (element k = (n>>8)&15)
#pragma unroll
    for (int b = 8; b < 12; b++) {
        GATES(b);
        const int pb = 1 << (b - 8);
#pragma unroll
        for (int k = 0; k < 16; k++)
            if (!(k & pb)) bfly(v[k], v[k | pb], g00, g01, g10, g11);
    }

    // store (L3 layout: lane-contiguous, coalesced)
#pragma unroll
    for (int k = 0; k < 16; k++)
        dst[base + (t | (k << 8))] = pack(v[k]);
}

// ---- pass B: butterflies on bits 12..17, then CNOT-chain scatter --------------
// 256 threads x 16 elems. Block = 64 contiguous lows x all 64 highs (bits 12..17).
// LAST=1: write sc*|amp| as f32 to out; else half2 state.
template<int LAST>
__global__ __launch_bounds__(256, 4) void passB(const unsigned* __restrict__ src,
                                                void* __restrict__ dst,
                                                const float4* __restrict__ Utab,
                                                const float* __restrict__ partials,
                                                int layer, Masks mk) {
    __shared__ unsigned sm[4096];   // 16 KB
    const int t = threadIdx.x;                 // 0..255
    const unsigned blk = blockIdx.x;           // 2048 blocks
    const unsigned batch = blk >> 6;
    const unsigned chunk = blk & 63;
    const unsigned low = chunk * 64 + (t & 63);   // 12-bit low index
    const unsigned j = t >> 6;                 // 0..3 (wave id)
    const size_t bb = (size_t)batch << NW;

    v2f v[16];
    // phase-1 ownership: h = (j<<4)|k  (k = h bits 0..3 = state bits 12..15)
#pragma unroll
    for (int k = 0; k < 16; k++) {
        unsigned h = (j << 4) | k;
        v[k] = unpack(src[bb + ((size_t)h << 12) + low]);
    }

    const float4* Ut = Utab + (size_t)layer * 36;
#pragma unroll
    for (int b = 12; b < 16; b++) {
        GATES(b);
        const int pb = 1 << (b - 12);
#pragma unroll
        for (int k = 0; k < 16; k++)
            if (!(k & pb)) bfly(v[k], v[k | pb], g00, g01, g10, g11);
    }

    // exchange: slot n = (h<<6) | (t&63); lanes consecutive -> conflict-free
#pragma unroll
    for (int k = 0; k < 16; k++) {
        unsigned h = (j << 4) | k;
        sm[(h << 6) | (t & 63)] = pack(v[k]);
    }
    __syncthreads();
    // phase-2 ownership: h = (q<<4) | (j<<2) | r, element idx = (q<<2)|r
#pragma unroll
    for (int q = 0; q < 4; q++)
#pragma unroll
        for (int r = 0; r < 4; r++) {
            unsigned h = (q << 4) | (j << 2) | r;
            v[(q << 2) | r] = unpack(sm[(h << 6) | (t & 63)]);
        }

    // bit 16 (wire 1): pairs idx, idx^4 ; bit 17 (wire 0): pairs idx, idx^8
    {
        GATES(16);
#pragma unroll
        for (int k = 0; k < 16; k++)
            if (!(k & 4)) bfly(v[k], v[k | 4], g00, g01, g10, g11);
    }
    {
        GATES(17);
#pragma unroll
        for (int k = 0; k < 16; k++)
            if (!(k & 8)) bfly(v[k], v[k | 8], g00, g01, g10, g11);
    }

    // scatter through GF(2)-linear CNOT map. Per-thread fixed part:
    unsigned f = 0;
#pragma unroll
    for (int kk = 0; kk < 12; kk++) f ^= ((low >> kk) & 1u) ? mk.m[kk] : 0u;
    if (j & 1) f ^= mk.m[14];
    if (j & 2) f ^= mk.m[15];

    float sc = 1.f;
    if (LAST) {
        float nrm = 0.f;
#pragma unroll
        for (int i = 0; i < 64; i++) nrm += partials[batch * 64 + i];
        sc = rsqrtf(nrm);
    }

    // element idx bits: r0->m12, r1->m13, q0->m16, q1->m17 ; gray-code walk
    const unsigned gm0 = mk.m[12], gm1 = mk.m[13], gm2 = mk.m[16], gm3 = mk.m[17];
    unsigned fs = f;
#pragma unroll
    for (int i = 0; i < 16; i++) {
        if (i) {
            const int c = ctzc(i);
            fs ^= (c == 0) ? gm0 : (c == 1) ? gm1 : (c == 2) ? gm2 : gm3;
        }
        const int s = i ^ (i >> 1);
        if (LAST) {
            ((float*)dst)[bb + fs] = sc * sqrtf(fmaf(v[s].x, v[s].x, v[s].y*v[s].y));
        } else {
            ((unsigned*)dst)[bb + fs] = pack(v[s]);
        }
    }
}

// ---- host: CNOT chain as an 18x18 GF(2) matrix -> column masks ----------------
static void chain_masks(int l, Masks* mk) {
    unsigned rows[18];
    for (int j = 0; j < 18; j++) rows[j] = 1u << j;      // new bit j as fn of old bits
    for (int i = 0; i < 18; i++) {
        int cw = (i + l) % 18, tw = (i + l + 1) % 18;    // wires
        rows[17 - tw] ^= rows[17 - cw];                  // bit_t ^= bit_c
    }
    for (int k = 0; k < 18; k++) {                       // transpose into column masks
        unsigned cm = 0;
        for (int j = 0; j < 18; j++) cm |= ((rows[j] >> k) & 1u) << j;
        mk->m[k] = cm;
    }
}

extern "C" void kernel_launch(void* const* d_in, const int* in_sizes, int n_in,
                              void* d_out, int out_size, void* d_ws, size_t ws_size,
                              hipStream_t stream) {
    const float* x      = (const float*)d_in[0];
    const float* params = (const float*)d_in[1];

    char* ws = (char*)d_ws;
    unsigned* bufA  = (unsigned*)ws;                     // 32 MB
    unsigned* bufB  = (unsigned*)(ws + TOTAL * 4);       // 32 MB
    float4*   Utab  = (float4*)(ws + TOTAL * 8);         // 72 * 16 B
    float* partials = (float*)(ws + TOTAL * 8 + 4096);   // 2048 f32

    Masks mk1, mk2;
    chain_masks(0, &mk1);
    chain_masks(1, &mk2);

    prep<<<1, 64, 0, stream>>>(params, Utab);
    normk<<<2048, 256, 0, stream>>>(x, partials);
    passA<1><<<2048, 256, 0, stream>>>((const void*)x, bufA, Utab, 0);
    passB<0><<<2048, 256, 0, stream>>>(bufA, (void*)bufB, Utab, partials, 0, mk1);
    passA<0><<<2048, 256, 0, stream>>>((const void*)bufB, bufB, Utab, 1);
    passB<1><<<2048, 256, 0, stream>>>(bufB, d_out, Utab, partials, 1, mk2);
}